// Round 2
// baseline (541.954 us; speedup 1.0000x reference)
//
#include <hip/hip_runtime.h>
#include <stdint.h>

typedef __bf16 bf16;
typedef __attribute__((ext_vector_type(8))) bf16 bf16x8;
typedef __attribute__((ext_vector_type(4))) float f32x4;

#define D 64
#define EPW 32   // edges per wave-tile

__device__ __forceinline__ float silu_f(float x) {
    return x / (1.0f + __expf(-x));
}

// ---------------------------------------------------------------------------
// Phase 1: per-edge message MLP (bf16 MFMA) + atomic scatter-add into agg.
// Wave-independent design: each wave owns a 32-edge tile (two 16-row MFMA
// halves). A-fragments are loaded DIRECTLY from global (lane (c,g) loads the
// 8 contiguous floats k'=32ks+8g..+7 of row c / row 16+c), so there is no
// X staging, no in-loop __syncthreads at all; Hs is a per-wave LDS region
// (intra-wave RAW ordered by compiler lgkmcnt).
// K-slot convention k' = 32*ks + 8*(lane>>4) + i used for BOTH A and B.
// C/D layout: col = nt*16 + (lane&15), row = 4*(lane>>4) + reg.
// ---------------------------------------------------------------------------
__launch_bounds__(256, 3)
__global__ void mp_edge_kernel(
    const float* __restrict__ node_feat,
    const int*   __restrict__ esrc,
    const int*   __restrict__ edst,
    const float* __restrict__ efeat,
    const float* __restrict__ W1, const float* __restrict__ b1,
    const float* __restrict__ W2, const float* __restrict__ b2,
    float* __restrict__ agg,
    int E)
{
    __shared__ __align__(16) bf16 W1f[6*4*64*8];   // 24 KB (ks,nt,lane,8)
    __shared__ __align__(16) bf16 W2f[2*4*64*8];   //  8 KB
    __shared__ __align__(16) bf16 Hs[4][32*72];    // 18 KB, per-wave 32x72
    __shared__ float b1s[D], b2s[D];

    const int t    = threadIdx.x;
    const int lane = t & 63;
    const int w    = t >> 6;
    const int g    = lane >> 4;
    const int c    = lane & 15;

    // ---- stage W1/W2 as MFMA B-fragments (once per block) ----
    for (int idx = t; idx < 6*4*64; idx += 256) {
        int l = idx & 63, nt = (idx >> 6) & 3, ks = idx >> 8;
        int k0 = ks*32 + (l >> 4)*8, col = nt*16 + (l & 15);
        bf16x8 v;
        #pragma unroll
        for (int i = 0; i < 8; ++i) v[i] = (bf16)W1[(k0 + i)*D + col];
        *(bf16x8*)&W1f[idx*8] = v;
    }
    for (int idx = t; idx < 2*4*64; idx += 256) {
        int l = idx & 63, nt = (idx >> 6) & 3, ks = idx >> 8;
        int k0 = ks*32 + (l >> 4)*8, col = nt*16 + (l & 15);
        bf16x8 v;
        #pragma unroll
        for (int i = 0; i < 8; ++i) v[i] = (bf16)W2[(k0 + i)*D + col];
        *(bf16x8*)&W2f[idx*8] = v;
    }
    if (t < D) { b1s[t] = b1[t]; b2s[t] = b2[t]; }
    __syncthreads();   // weights ready; the ONLY barrier in the kernel

    bf16* hs = &Hs[w][0];
    const int nwt = (E + EPW - 1) / EPW;

    for (int tile = blockIdx.x*4 + w; tile < nwt; tile += gridDim.x*4) {
        const int e0 = tile * EPW;
        const int r0 = min(e0 + c,      E - 1);
        const int r1 = min(e0 + 16 + c, E - 1);
        const int se0 = esrc[r0], de0 = edst[r0];
        const int se1 = esrc[r1], de1 = edst[r1];

        // ---- GEMM1: [32,192]@[192,64], A direct from global ----
        f32x4 acc0[4] = {f32x4{0,0,0,0}, f32x4{0,0,0,0}, f32x4{0,0,0,0}, f32x4{0,0,0,0}};
        f32x4 acc1[4] = {f32x4{0,0,0,0}, f32x4{0,0,0,0}, f32x4{0,0,0,0}, f32x4{0,0,0,0}};
        #pragma unroll
        for (int ks = 0; ks < 6; ++ks) {
            const int col = ks*32 + g*8;
            const float *p0, *p1;
            if (col < 64) {
                p0 = node_feat + (size_t)se0*D + col;
                p1 = node_feat + (size_t)se1*D + col;
            } else if (col < 128) {
                p0 = node_feat + (size_t)de0*D + (col - 64);
                p1 = node_feat + (size_t)de1*D + (col - 64);
            } else {
                p0 = efeat + (size_t)r0*D + (col - 128);
                p1 = efeat + (size_t)r1*D + (col - 128);
            }
            f32x4 xa = ((const f32x4*)p0)[0], xb = ((const f32x4*)p0)[1];
            f32x4 ya = ((const f32x4*)p1)[0], yb = ((const f32x4*)p1)[1];
            bf16x8 a0, a1;
            #pragma unroll
            for (int i = 0; i < 4; ++i) {
                a0[i] = (bf16)xa[i];  a0[4+i] = (bf16)xb[i];
                a1[i] = (bf16)ya[i];  a1[4+i] = (bf16)yb[i];
            }
            #pragma unroll
            for (int n = 0; n < 4; ++n) {
                bf16x8 bb = *(const bf16x8*)&W1f[((ks*4 + n)*64 + lane)*8];
                acc0[n] = __builtin_amdgcn_mfma_f32_16x16x32_bf16(a0, bb, acc0[n], 0, 0, 0);
                acc1[n] = __builtin_amdgcn_mfma_f32_16x16x32_bf16(a1, bb, acc1[n], 0, 0, 0);
            }
        }

        // ---- bias + SiLU -> per-wave Hs (bf16) ----
        #pragma unroll
        for (int n = 0; n < 4; ++n) {
            const int col = n*16 + c;
            const float bias = b1s[col];
            #pragma unroll
            for (int j = 0; j < 4; ++j) {
                hs[(g*4 + j)*72 + col]        = (bf16)silu_f(acc0[n][j] + bias);
                hs[(16 + g*4 + j)*72 + col]   = (bf16)silu_f(acc1[n][j] + bias);
            }
        }

        // ---- GEMM2: [32,64]@[64,64] (intra-wave LDS ordering, no barrier) ----
        f32x4 acc2a[4] = {f32x4{0,0,0,0}, f32x4{0,0,0,0}, f32x4{0,0,0,0}, f32x4{0,0,0,0}};
        f32x4 acc2b[4] = {f32x4{0,0,0,0}, f32x4{0,0,0,0}, f32x4{0,0,0,0}, f32x4{0,0,0,0}};
        #pragma unroll
        for (int ks = 0; ks < 2; ++ks) {
            bf16x8 a0 = *(const bf16x8*)&hs[c*72        + ks*32 + g*8];
            bf16x8 a1 = *(const bf16x8*)&hs[(16 + c)*72 + ks*32 + g*8];
            #pragma unroll
            for (int n = 0; n < 4; ++n) {
                bf16x8 bb = *(const bf16x8*)&W2f[((ks*4 + n)*64 + lane)*8];
                acc2a[n] = __builtin_amdgcn_mfma_f32_16x16x32_bf16(a0, bb, acc2a[n], 0, 0, 0);
                acc2b[n] = __builtin_amdgcn_mfma_f32_16x16x32_bf16(a1, bb, acc2b[n], 0, 0, 0);
            }
        }

        // ---- bias + atomic scatter-add ----
        #pragma unroll
        for (int j = 0; j < 4; ++j) {
            const int row = g*4 + j;
            const int d0 = __shfl(de0, row);        // lane 'row' holds edst[e0+row]
            const int d1 = __shfl(de1, row);
            const bool ok0 = (e0 + row)      < E;
            const bool ok1 = (e0 + 16 + row) < E;
            #pragma unroll
            for (int n = 0; n < 4; ++n) {
                const int col = n*16 + c;
                if (ok0) atomicAdd(&agg[(size_t)d0*D + col], acc2a[n][j] + b2s[col]);
                if (ok1) atomicAdd(&agg[(size_t)d1*D + col], acc2b[n][j] + b2s[col]);
            }
        }
    }
}

// ---------------------------------------------------------------------------
// Phase 2: per-node update MLP (fp32) + residual + LayerNorm, in-place on agg.
// One wave per node; lane j owns output dim j; k-broadcast via __shfl.
// ---------------------------------------------------------------------------
__launch_bounds__(256, 4)
__global__ void mp_node_kernel(
    const float* __restrict__ node_feat,
    const float* __restrict__ Wu1, const float* __restrict__ bu1,
    const float* __restrict__ Wu2, const float* __restrict__ bu2,
    const float* __restrict__ gamma, const float* __restrict__ beta,
    float* __restrict__ inout,     // agg on entry, final output on exit
    int nnodes)
{
    __shared__ __align__(16) float W1t[64*68];   // transposed [j][k], stride 68
    __shared__ __align__(16) float W2t[64*68];
    __shared__ float b1s[D], b2s[D], gs[D], bs[D];

    const int t = threadIdx.x, lane = t & 63, w = t >> 6;
    for (int idx = t; idx < 4096; idx += 256) {
        int j = idx & 63, k = idx >> 6;          // coalesced global reads
        W1t[j*68 + k] = Wu1[k*D + j];
        W2t[j*68 + k] = Wu2[k*D + j];
    }
    if (t < D) { b1s[t] = bu1[t]; b2s[t] = bu2[t]; gs[t] = gamma[t]; bs[t] = beta[t]; }
    __syncthreads();

    for (int n = blockIdx.x*4 + w; n < nnodes; n += gridDim.x*4) {
        float a  = inout[(size_t)n*D + lane];
        float x0 = node_feat[(size_t)n*D + lane];

        float acc = b1s[lane];
        #pragma unroll
        for (int k4 = 0; k4 < 16; ++k4) {
            f32x4 wv = *(const f32x4*)&W1t[lane*68 + k4*4];
            acc += __shfl(a, k4*4+0)*wv[0] + __shfl(a, k4*4+1)*wv[1]
                 + __shfl(a, k4*4+2)*wv[2] + __shfl(a, k4*4+3)*wv[3];
        }
        float h = silu_f(acc);

        float acc2 = b2s[lane];
        #pragma unroll
        for (int k4 = 0; k4 < 16; ++k4) {
            f32x4 wv = *(const f32x4*)&W2t[lane*68 + k4*4];
            acc2 += __shfl(h, k4*4+0)*wv[0] + __shfl(h, k4*4+1)*wv[1]
                  + __shfl(h, k4*4+2)*wv[2] + __shfl(h, k4*4+3)*wv[3];
        }

        float y = x0 + acc2;
        float s1 = y, s2 = y*y;
        #pragma unroll
        for (int off = 32; off > 0; off >>= 1) {
            s1 += __shfl_xor(s1, off);
            s2 += __shfl_xor(s2, off);
        }
        float mu  = s1 * (1.0f/64.0f);
        float var = s2 * (1.0f/64.0f) - mu*mu;
        float rs  = rsqrtf(var + 1e-5f);
        inout[(size_t)n*D + lane] = (y - mu)*rs*gs[lane] + bs[lane];
    }
}

extern "C" void kernel_launch(void* const* d_in, const int* in_sizes, int n_in,
                              void* d_out, int out_size, void* d_ws, size_t ws_size,
                              hipStream_t stream) {
    const float* node_feat = (const float*)d_in[0];
    const int*   esrc      = (const int*)d_in[1];
    const int*   edst      = (const int*)d_in[2];
    const float* efeat     = (const float*)d_in[3];
    const float* W_m1      = (const float*)d_in[4];
    const float* b_m1      = (const float*)d_in[5];
    const float* W_m2      = (const float*)d_in[6];
    const float* b_m2      = (const float*)d_in[7];
    const float* W_u1      = (const float*)d_in[8];
    const float* b_u1      = (const float*)d_in[9];
    const float* W_u2      = (const float*)d_in[10];
    const float* b_u2      = (const float*)d_in[11];
    const float* ln_gamma  = (const float*)d_in[12];
    const float* ln_beta   = (const float*)d_in[13];

    float* out = (float*)d_out;
    const int E      = in_sizes[1];
    const int nnodes = in_sizes[0] / D;

    // agg accumulates directly into d_out; phase 2 rewrites it in place
    hipMemsetAsync(out, 0, (size_t)nnodes * D * sizeof(float), stream);

    const int nwt   = (E + EPW - 1) / EPW;           // wave-tiles
    const int nblk  = (nwt + 3) / 4;
    const int grid1 = nblk < 2048 ? nblk : 2048;
    mp_edge_kernel<<<grid1, 256, 0, stream>>>(node_feat, esrc, edst, efeat,
                                              W_m1, b_m1, W_m2, b_m2,
                                              out, E);

    mp_node_kernel<<<2048, 256, 0, stream>>>(node_feat, W_u1, b_u1, W_u2, b_u2,
                                             ln_gamma, ln_beta, out, nnodes);
}